// Round 3
// baseline (1346.005 us; speedup 1.0000x reference)
//
#include <hip/hip_runtime.h>
#include <hip/hip_bf16.h>

// Problem constants: B=4, C_IN=C_OUT=64, N=100000, K=6
#define BB   4
#define NN   100000
#define KK   6
#define EPSV 1e-5f

using bf16   = __hip_bfloat16;
using ushort = unsigned short;
typedef __attribute__((ext_vector_type(8))) short  short8;   // 8 bf16 = 4 VGPRs
typedef __attribute__((ext_vector_type(4))) float  float4v;  // MFMA C/D

union U4S8 { uint4 u; short8 s; };

__device__ __forceinline__ float blo(unsigned x) {           // low bf16 -> f32
    union { unsigned u; float f; } c; c.u = x << 16; return c.f;
}
__device__ __forceinline__ float bhi(unsigned x) {           // high bf16 -> f32
    union { unsigned u; float f; } c; c.u = x & 0xFFFF0000u; return c.f;
}
__device__ __forceinline__ unsigned f2bu(float f) {          // f32 -> raw bf16 RNE
    union { bf16 h; ushort u; } c; c.h = __float2bfloat16(f); return c.u;
}
__device__ __forceinline__ unsigned pk(float a, float b) {
    return f2bu(a) | (f2bu(b) << 16);
}
__device__ __forceinline__ unsigned relu2(unsigned x) {      // relu on packed 2xbf16
    unsigned lo = (unsigned)(((int)(x << 16)) >> 31) & 0x0000FFFFu;
    unsigned hi = ((unsigned)(((int)x) >> 31)) << 16;
    return x & ~(lo | hi);
}

// ---------------------------------------------------------------------------
// wprep0: swizzle W0[o][c][2] into MFMA M-operand fragments for GEMM1.
// Wf0[((t*2+s)*64+lane)*8+i] = W0[o=(t&3)*16+(lane&15)][c=s*32+(lane>>4)*8+i][t>>2]
// (tiles t<4 produce u = x·We, t>=4 produce v = x·Wo)
// ---------------------------------------------------------------------------
__global__ void wprep0_k(const float* __restrict__ W0, ushort* __restrict__ Wf0)
{
    int L = blockIdx.x * 256 + threadIdx.x;        // 8192
    if (L < 8192) {
        int i = L & 7, lane = (L >> 3) & 63, r = L >> 9;
        int s = r & 1, t = r >> 1;
        int o = (t & 3) * 16 + (lane & 15);
        int c = s * 32 + (lane >> 4) * 8 + i;
        Wf0[L] = f2bu(W0[o * 128 + c * 2 + (t >> 2)]);
    }
}

// ---------------------------------------------------------------------------
// xpose: x [B,C,N] f32 -> xT [B,N,C] bf16.
// ---------------------------------------------------------------------------
__global__ __launch_bounds__(256) void xpose_k(const float* __restrict__ x,
                                               ushort* __restrict__ xT)
{
    __shared__ float tile[64][65];
    const int b  = blockIdx.y;
    const int n0 = blockIdx.x * 64;
    const int tx = threadIdx.x & 63;
    const int ty = threadIdx.x >> 6;
    const float* xb = x + (size_t)b * 64 * NN;
    const int n = n0 + tx;
#pragma unroll
    for (int cc = 0; cc < 64; cc += 4) {
        const int c = cc + ty;
        tile[tx][c] = (n < NN) ? xb[(size_t)c * NN + n] : 0.f;
    }
    __syncthreads();
#pragma unroll
    for (int rr = 0; rr < 64; rr += 4) {
        const int nl = rr + ty;
        const int n2 = n0 + nl;
        if (n2 < NN) xT[((size_t)b * NN + n2) * 64 + tx] = (ushort)f2bu(tile[nl][tx]);
    }
}

// ---------------------------------------------------------------------------
// GEMM1: U[g][128] = [ xT[g]·We | xT[g]·Wo ]  (bf16, row = 256B).
// Pure streaming: weights in 64 VGPRs, A-frags direct global b128, no LDS.
// 25000 tiles of 16 points, 2500 waves x 10 tiles.
// ---------------------------------------------------------------------------
__global__ __launch_bounds__(256, 3) void gemm1_k(
    const ushort* __restrict__ xT, const ushort* __restrict__ Wf,
    ushort* __restrict__ U)
{
    const int wave = threadIdx.x >> 6;
    const int lane = threadIdx.x & 63;
    const int col  = lane & 15;
    const int quad = lane >> 4;

    short8 wf[8][2];
#pragma unroll
    for (int t = 0; t < 8; ++t)
#pragma unroll
        for (int s = 0; s < 2; ++s)
            wf[t][s] = *(const short8*)(Wf + ((t * 2 + s) * 64 + lane) * 8);

    const int wid = blockIdx.x * 4 + wave;            // 2500 waves
    for (int tile = wid; tile < 25000; tile += 2500) {
        const size_t g0 = (size_t)tile * 16;
        const ushort* ar = xT + (g0 + col) * 64 + quad * 8;
        short8 p0 = *(const short8*)(ar);
        short8 p1 = *(const short8*)(ar + 32);

        float4v acc[8];
#pragma unroll
        for (int t = 0; t < 8; ++t) acc[t] = (float4v){0.f, 0.f, 0.f, 0.f};
#pragma unroll
        for (int t = 0; t < 8; ++t)
            acc[t] = __builtin_amdgcn_mfma_f32_16x16x32_bf16(wf[t][0], p0, acc[t], 0, 0, 0);
#pragma unroll
        for (int t = 0; t < 8; ++t)
            acc[t] = __builtin_amdgcn_mfma_f32_16x16x32_bf16(wf[t][1], p1, acc[t], 0, 0, 0);

        // D[row=quad*4+r -> ch_local][col -> point]; lane packs 4 consecutive ch
        ushort* urow = U + (g0 + col) * 128 + quad * 4;
#pragma unroll
        for (int t = 0; t < 8; ++t) {
            uint2 d;
            d.x = pk(acc[t][0], acc[t][1]);
            d.y = pk(acc[t][2], acc[t][3]);
            *(uint2*)(urow + t * 16) = d;
        }
    }
}

// ---------------------------------------------------------------------------
// gather1: h[g] = u[g] + sum_k v[nb_k]; write hT bf16 (pre-relu, residual) and
// BN stats (sum, sumsq of relu). Streaming, no LDS, no barriers.
// 50000 groups of 8 points, 5000 waves x 10 groups.
// ---------------------------------------------------------------------------
__global__ __launch_bounds__(256) void gather1_k(
    const ushort* __restrict__ U, const int* __restrict__ neigh,
    ushort* __restrict__ hT, float* __restrict__ stats)
{
    const int wave = threadIdx.x >> 6;
    const int lane = threadIdx.x & 63;
    const int slot = lane >> 3;
    const int sub  = lane & 7;
    const int wid  = blockIdx.x * 4 + wave;           // 5000 waves

    float sA[8] = {0, 0, 0, 0, 0, 0, 0, 0};
    float sB[8] = {0, 0, 0, 0, 0, 0, 0, 0};

#pragma unroll 2
    for (unsigned grp = wid; grp < 50000u; grp += 5000u) {
        const unsigned g0 = grp * 8u;
        const unsigned b  = g0 / (unsigned)NN;        // groups never cross batch
        const int ii = neigh[(size_t)g0 * 6 + (lane < 48 ? lane : 47)];
        const size_t g = g0 + slot;

        uint4 uu = *(const uint4*)(U + g * 128 + sub * 8);
        float h[8];
        h[0] = blo(uu.x); h[1] = bhi(uu.x); h[2] = blo(uu.y); h[3] = bhi(uu.y);
        h[4] = blo(uu.z); h[5] = bhi(uu.z); h[6] = blo(uu.w); h[7] = bhi(uu.w);

#pragma unroll
        for (int k = 0; k < KK; ++k) {
            const int idx = __shfl(ii, slot * 6 + k);
            const size_t vr = (size_t)b * NN + idx;
            uint4 vv = *(const uint4*)(U + vr * 128 + 64 + sub * 8);
            h[0] += blo(vv.x); h[1] += bhi(vv.x); h[2] += blo(vv.y); h[3] += bhi(vv.y);
            h[4] += blo(vv.z); h[5] += bhi(vv.z); h[6] += blo(vv.w); h[7] += bhi(vv.w);
        }

        uint4 st;
        st.x = pk(h[0], h[1]); st.y = pk(h[2], h[3]);
        st.z = pk(h[4], h[5]); st.w = pk(h[6], h[7]);
        *(uint4*)(hT + g * 64 + sub * 8) = st;

#pragma unroll
        for (int j = 0; j < 8; ++j) {
            float rv = fmaxf(h[j], 0.f);
            sA[j] += rv;
            sB[j]  = fmaf(rv, rv, sB[j]);
        }
    }

    // reduce across the 8 slots (xor butterfly over lane bits 3..5)
#pragma unroll
    for (int d = 8; d < 64; d <<= 1)
#pragma unroll
        for (int j = 0; j < 8; ++j) {
            sA[j] += __shfl_xor(sA[j], d);
            sB[j] += __shfl_xor(sB[j], d);
        }
    if (slot == 0) {
#pragma unroll
        for (int j = 0; j < 8; ++j) {
            atomicAdd(&stats[sub * 8 + j], sA[j]);
            atomicAdd(&stats[64 + sub * 8 + j], sB[j]);
        }
    }
}

// ---------------------------------------------------------------------------
// bnprep: fold BN into conv2. a=gamma*rsqrt(var+eps), b=beta-a*mean.
// Wf1 = swizzled a_c * W1;  bias[128] = [ sum_c b_c*We1[c][o] | sum_c b_c*Wo1 ]
// (bias init of u-acc / v-acc makes gather2 = p + sum q + residual, no extra).
// Single block: stats -> a,b in LDS -> swizzle + bias.
// ---------------------------------------------------------------------------
__global__ __launch_bounds__(256) void bnprep_k(
    const float* __restrict__ stats, const float* __restrict__ gamma,
    const float* __restrict__ beta, const float* __restrict__ W1,
    ushort* __restrict__ Wf1, float* __restrict__ bias)
{
    __shared__ float a_s[64], b_s[64];
    const int tid = threadIdx.x;
    if (tid < 64) {
        const float inv = 1.f / (float)(BB * NN);
        float mean = stats[tid] * inv;
        float var  = stats[64 + tid] * inv - mean * mean;   // biased var (jnp.var)
        float a    = gamma[tid] * rsqrtf(var + EPSV);
        a_s[tid] = a;
        b_s[tid] = fmaf(-a, mean, beta[tid]);
    }
    __syncthreads();

    for (int L = tid; L < 8192; L += 256) {
        int i = L & 7, lane = (L >> 3) & 63, r = L >> 9;
        int s = r & 1, t = r >> 1;
        int o = (t & 3) * 16 + (lane & 15);
        int c = s * 32 + (lane >> 4) * 8 + i;
        Wf1[L] = f2bu(a_s[c] * W1[o * 128 + c * 2 + (t >> 2)]);
    }
    if (tid < 128) {
        const int part = tid >> 6, o = tid & 63;
        float s = 0.f;
        for (int c = 0; c < 64; ++c)
            s = fmaf(b_s[c], W1[o * 128 + c * 2 + part], s);
        bias[tid] = s;
    }
}

// ---------------------------------------------------------------------------
// GEMM2: U2[g][128] = [ relu(hT[g])·We1' + biasE | relu(hT[g])·Wo1' + biasO ].
// Same structure as GEMM1; packed-bf16 relu on the A fragments.
// ---------------------------------------------------------------------------
__global__ __launch_bounds__(256, 3) void gemm2_k(
    const ushort* __restrict__ hT, const ushort* __restrict__ Wf,
    const float* __restrict__ bias, ushort* __restrict__ U2)
{
    const int wave = threadIdx.x >> 6;
    const int lane = threadIdx.x & 63;
    const int col  = lane & 15;
    const int quad = lane >> 4;

    short8 wf[8][2];
#pragma unroll
    for (int t = 0; t < 8; ++t)
#pragma unroll
        for (int s = 0; s < 2; ++s)
            wf[t][s] = *(const short8*)(Wf + ((t * 2 + s) * 64 + lane) * 8);

    float4v binit[8];
#pragma unroll
    for (int t = 0; t < 8; ++t)
#pragma unroll
        for (int r = 0; r < 4; ++r)
            binit[t][r] = bias[t * 16 + quad * 4 + r];

    const int wid = blockIdx.x * 4 + wave;
    for (int tile = wid; tile < 25000; tile += 2500) {
        const size_t g0 = (size_t)tile * 16;
        const ushort* ar = hT + (g0 + col) * 64 + quad * 8;
        U4S8 p0, p1;
        p0.u = *(const uint4*)(ar);
        p1.u = *(const uint4*)(ar + 32);
        p0.u.x = relu2(p0.u.x); p0.u.y = relu2(p0.u.y);
        p0.u.z = relu2(p0.u.z); p0.u.w = relu2(p0.u.w);
        p1.u.x = relu2(p1.u.x); p1.u.y = relu2(p1.u.y);
        p1.u.z = relu2(p1.u.z); p1.u.w = relu2(p1.u.w);

        float4v acc[8];
#pragma unroll
        for (int t = 0; t < 8; ++t) acc[t] = binit[t];
#pragma unroll
        for (int t = 0; t < 8; ++t)
            acc[t] = __builtin_amdgcn_mfma_f32_16x16x32_bf16(wf[t][0], p0.s, acc[t], 0, 0, 0);
#pragma unroll
        for (int t = 0; t < 8; ++t)
            acc[t] = __builtin_amdgcn_mfma_f32_16x16x32_bf16(wf[t][1], p1.s, acc[t], 0, 0, 0);

        ushort* urow = U2 + (g0 + col) * 128 + quad * 4;
#pragma unroll
        for (int t = 0; t < 8; ++t) {
            uint2 d;
            d.x = pk(acc[t][0], acc[t][1]);
            d.y = pk(acc[t][2], acc[t][3]);
            *(uint2*)(urow + t * 16) = d;
        }
    }
}

// ---------------------------------------------------------------------------
// gather2: o[n] = relu( p[n] + sum_k q[nb_k] + h_res[n] ), staged through an
// LDS tile (64 points x 64 ch) and stored transposed/coalesced to [B,O,N] f32.
// ---------------------------------------------------------------------------
__global__ __launch_bounds__(256) void gather2_k(
    const ushort* __restrict__ U2, const ushort* __restrict__ hT,
    const int* __restrict__ neigh, float* __restrict__ out)
{
    __shared__ float ts[64 * 65];
    const int b    = blockIdx.y;
    const int n0   = blockIdx.x * 64;
    const int wave = threadIdx.x >> 6;
    const int lane = threadIdx.x & 63;
    const int slot = lane >> 3;
    const int sub  = lane & 7;

#pragma unroll
    for (int grp = 0; grp < 2; ++grp) {
        const int p  = wave * 16 + grp * 8 + slot;
        const int n  = n0 + p;
        const int nc = (n < NN) ? n : (NN - 1);
        const size_t g = (size_t)b * NN + nc;

        // 48 neighbor indices for this wave-group (per-lane linear, clamped)
        const int l  = (lane < 48) ? lane : 47;
        const int sl = l / 6, kl = l - sl * 6;
        int pt = n0 + wave * 16 + grp * 8 + sl;
        if (pt > NN - 1) pt = NN - 1;
        const int ii = neigh[((size_t)b * NN + pt) * 6 + kl];

        uint4 pp = *(const uint4*)(U2 + g * 128 + sub * 8);
        uint4 hh = *(const uint4*)(hT + g * 64 + sub * 8);
        float h[8];
        h[0] = blo(pp.x) + blo(hh.x); h[1] = bhi(pp.x) + bhi(hh.x);
        h[2] = blo(pp.y) + blo(hh.y); h[3] = bhi(pp.y) + bhi(hh.y);
        h[4] = blo(pp.z) + blo(hh.z); h[5] = bhi(pp.z) + bhi(hh.z);
        h[6] = blo(pp.w) + blo(hh.w); h[7] = bhi(pp.w) + bhi(hh.w);

#pragma unroll
        for (int k = 0; k < KK; ++k) {
            const int idx = __shfl(ii, slot * 6 + k);
            const size_t vr = (size_t)b * NN + idx;
            uint4 qq = *(const uint4*)(U2 + vr * 128 + 64 + sub * 8);
            h[0] += blo(qq.x); h[1] += bhi(qq.x); h[2] += blo(qq.y); h[3] += bhi(qq.y);
            h[4] += blo(qq.z); h[5] += bhi(qq.z); h[6] += blo(qq.w); h[7] += bhi(qq.w);
        }

#pragma unroll
        for (int j = 0; j < 8; ++j)
            ts[(sub * 8 + j) * 65 + p] = fmaxf(h[j], 0.f);
    }
    __syncthreads();

    const int n = n0 + lane;
    if (n < NN) {
#pragma unroll
        for (int rr = 0; rr < 16; ++rr) {
            const int o = wave * 16 + rr;
            out[((size_t)b * 64 + o) * NN + n] = ts[o * 65 + lane];
        }
    }
}

// ---------------------------------------------------------------------------
// Workspace (bytes), peak ~153.6 MB:
//   [0, 51.2M)      xT bf16 (dead after GEMM1) -- overlapped by U2
//   [0, 102.4M)     U2 bf16 (written by GEMM2)
//   [102.4M,153.6M) hT bf16 (alive GEMM1..gather2)
//   153,600,000 stats[128]; 153,600,512 bias[128];
//   153,601,024 Wf0; 153,617,408 Wf1   (end 153,633,792)
// U1 (GEMM1 output) lives in d_out (dead before gather2 rewrites d_out).
// ---------------------------------------------------------------------------
extern "C" void kernel_launch(void* const* d_in, const int* in_sizes, int n_in,
                              void* d_out, int out_size, void* d_ws, size_t ws_size,
                              hipStream_t stream)
{
    const float* x     = (const float*)d_in[0];
    const int*   neigh = (const int*)d_in[1];
    const float* W0    = (const float*)d_in[2];
    const float* W1    = (const float*)d_in[3];
    const float* gamma = (const float*)d_in[4];
    const float* beta  = (const float*)d_in[5];
    float* out = (float*)d_out;

    char* ws = (char*)d_ws;
    ushort* xT    = (ushort*)(ws + 0);
    ushort* U2    = (ushort*)(ws + 0);
    ushort* hT    = (ushort*)(ws + 102400000);
    float*  stats = (float*)(ws + 153600000);
    float*  bias  = (float*)(ws + 153600512);
    ushort* Wf0   = (ushort*)(ws + 153601024);
    ushort* Wf1   = (ushort*)(ws + 153617408);
    ushort* U1    = (ushort*)d_out;

    hipMemsetAsync(stats, 0, 512, stream);
    wprep0_k<<<dim3(32), dim3(256), 0, stream>>>(W0, Wf0);
    xpose_k<<<dim3((NN + 63) / 64, BB), dim3(256), 0, stream>>>(x, xT);
    gemm1_k<<<dim3(625), dim3(256), 0, stream>>>(xT, Wf0, U1);
    gather1_k<<<dim3(1250), dim3(256), 0, stream>>>(U1, neigh, hT, stats);
    bnprep_k<<<dim3(1), dim3(256), 0, stream>>>(stats, gamma, beta, W1, Wf1, bias);
    gemm2_k<<<dim3(625), dim3(256), 0, stream>>>(hT, Wf1, bias, U2);
    gather2_k<<<dim3((NN + 63) / 64, BB), dim3(256), 0, stream>>>(U2, hT, neigh, out);
}

// Round 4
// 718.676 us; speedup vs baseline: 1.8729x; 1.8729x over previous
//
#include <hip/hip_runtime.h>
#include <hip/hip_bf16.h>

// Problem constants: B=4, C_IN=C_OUT=64, N=100000, K=6
#define BB   4
#define NN   100000
#define TOT  (BB * NN)          // 400000
#define KK   6
#define EPSV 1e-5f

using bf16   = __hip_bfloat16;
using ushort = unsigned short;
typedef __attribute__((ext_vector_type(8))) short  short8;   // 8 bf16 = 4 VGPRs
typedef __attribute__((ext_vector_type(4))) float  float4v;  // MFMA C/D

union U4S8 { uint4 u; short8 s; };

__device__ __forceinline__ unsigned f2bu(float f) {          // f32 -> raw bf16 RNE
    union { bf16 h; ushort u; } c; c.h = __float2bfloat16(f); return c.u;
}
__device__ __forceinline__ unsigned pk(float a, float b) {
    return f2bu(a) | (f2bu(b) << 16);
}
__device__ __forceinline__ float ldb(const ushort* p) {      // bf16 load -> f32
    union { unsigned u; float f; } c; c.u = ((unsigned)*p) << 16; return c.f;
}
__device__ __forceinline__ unsigned relu2(unsigned x) {      // relu on packed 2xbf16
    unsigned lo = (unsigned)(((int)(x << 16)) >> 31) & 0x0000FFFFu;
    unsigned hi = ((unsigned)(((int)x) >> 31)) << 16;
    return x & ~(lo | hi);
}
__device__ __forceinline__ int batch_base(int g) {           // (g/NN)*NN via compares
    return (g >= 3 * NN) ? 3 * NN : (g >= 2 * NN) ? 2 * NN : (g >= NN) ? NN : 0;
}

// ---------------------------------------------------------------------------
// wprep0: swizzle W0[o][c][2] into MFMA M-operand (B-role) fragments.
// Wf0[((t*2+s)*64+lane)*8+i] = W0[o=(t&3)*16+(lane&15)][c=s*32+(lane>>4)*8+i][t>>2]
// tiles t<4 -> u = x·We (center), t>=4 -> v = x·Wo (neighbor operator).
// ---------------------------------------------------------------------------
__global__ void wprep0_k(const float* __restrict__ W0, ushort* __restrict__ Wf0)
{
    int L = blockIdx.x * 256 + threadIdx.x;        // 8192
    if (L < 8192) {
        int i = L & 7, lane = (L >> 3) & 63, r = L >> 9;
        int s = r & 1, t = r >> 1;
        int o = (t & 3) * 16 + (lane & 15);
        int c = s * 32 + (lane >> 4) * 8 + i;
        Wf0[L] = f2bu(W0[o * 128 + c * 2 + (t >> 2)]);
    }
}

// ---------------------------------------------------------------------------
// xpose: x [B,C,N] f32 -> xT [B,N,C] bf16.
// ---------------------------------------------------------------------------
__global__ __launch_bounds__(256) void xpose_k(const float* __restrict__ x,
                                               ushort* __restrict__ xT)
{
    __shared__ float tile[64][65];
    const int b  = blockIdx.y;
    const int n0 = blockIdx.x * 64;
    const int tx = threadIdx.x & 63;
    const int ty = threadIdx.x >> 6;
    const float* xb = x + (size_t)b * 64 * NN;
    const int n = n0 + tx;
#pragma unroll
    for (int cc = 0; cc < 64; cc += 4) {
        const int c = cc + ty;
        tile[tx][c] = (n < NN) ? xb[(size_t)c * NN + n] : 0.f;
    }
    __syncthreads();
#pragma unroll
    for (int rr = 0; rr < 64; rr += 4) {
        const int nl = rr + ty;
        const int n2 = n0 + nl;
        if (n2 < NN) xT[((size_t)b * NN + n2) * 64 + tx] = (ushort)f2bu(tile[nl][tx]);
    }
}

// ---------------------------------------------------------------------------
// GEMM1: Uu[g][64] = xT[g]·We ; Uv[g][64] = xT[g]·Wo  (bf16 rows, 128 B).
// Streaming MFMA: weights in 64 VGPRs, A-frags direct global b128, no LDS.
// ---------------------------------------------------------------------------
__global__ __launch_bounds__(256, 3) void gemm1_k(
    const ushort* __restrict__ xT, const ushort* __restrict__ Wf,
    ushort* __restrict__ Uu, ushort* __restrict__ Uv)
{
    const int wave = threadIdx.x >> 6;
    const int lane = threadIdx.x & 63;
    const int col  = lane & 15;
    const int quad = lane >> 4;

    short8 wf[8][2];
#pragma unroll
    for (int t = 0; t < 8; ++t)
#pragma unroll
        for (int s = 0; s < 2; ++s)
            wf[t][s] = *(const short8*)(Wf + ((t * 2 + s) * 64 + lane) * 8);

    const int wid = blockIdx.x * 4 + wave;            // 2500 waves, 10 tiles each
    for (int tile = wid; tile < 25000; tile += 2500) {
        const size_t g0 = (size_t)tile * 16;
        const ushort* ar = xT + (g0 + col) * 64 + quad * 8;
        short8 p0 = *(const short8*)(ar);
        short8 p1 = *(const short8*)(ar + 32);

        float4v acc[8];
#pragma unroll
        for (int t = 0; t < 8; ++t) acc[t] = (float4v){0.f, 0.f, 0.f, 0.f};
#pragma unroll
        for (int t = 0; t < 8; ++t)
            acc[t] = __builtin_amdgcn_mfma_f32_16x16x32_bf16(wf[t][0], p0, acc[t], 0, 0, 0);
#pragma unroll
        for (int t = 0; t < 8; ++t)
            acc[t] = __builtin_amdgcn_mfma_f32_16x16x32_bf16(wf[t][1], p1, acc[t], 0, 0, 0);

        // D[row=quad*4+r -> ch][col -> point]
#pragma unroll
        for (int t = 0; t < 8; ++t) {
            uint2 d;
            d.x = pk(acc[t][0], acc[t][1]);
            d.y = pk(acc[t][2], acc[t][3]);
            ushort* base = (t < 4) ? Uu : Uv;
            *(uint2*)(base + (g0 + col) * 64 + (t & 3) * 16 + quad * 4) = d;
        }
    }
}

// ---------------------------------------------------------------------------
// gather1: h[g] = u[g] + sum_k v[nb_k]. Wave-uniform point loop (idx loads are
// same-address broadcasts — NO shfl), explicit load batching (all 56 loads of
// an 8-point group issued before any consumption), no atomics (per-block
// partial stats -> ws). lane = channel. Writes hT bf16 (pre-relu; residual &
// gemm2 input) + partials[block][128] (sum, sumsq of relu).
// ---------------------------------------------------------------------------
__global__ __launch_bounds__(256, 4) void gather1_k(
    const ushort* __restrict__ Uu, const ushort* __restrict__ Uv,
    const int* __restrict__ neigh, ushort* __restrict__ hT,
    float* __restrict__ partials)
{
    __shared__ float red[4][128];
    const int wave = threadIdx.x >> 6;
    const int lane = threadIdx.x & 63;
    const int g0   = (blockIdx.x * 4 + wave) * 64;   // this wave's 64 points
    float sA = 0.f, sB = 0.f;

    for (int it = 0; it < 8; ++it) {
        const int gb = g0 + it * 8;
        float u[8], v[8][6];
        // ---- phase 1: issue all 8+48 loads (independent across points) ----
#pragma unroll
        for (int p = 0; p < 8; ++p) {
            const int g  = gb + p;
            const int gc = (g < TOT) ? g : (TOT - 1);
            const int bo = batch_base(gc);
            const int* nb = neigh + (size_t)gc * 6;
            u[p] = ldb(Uu + (size_t)gc * 64 + lane);
            int i0 = nb[0], i1 = nb[1], i2 = nb[2], i3 = nb[3], i4 = nb[4], i5 = nb[5];
            v[p][0] = ldb(Uv + (size_t)(bo + i0) * 64 + lane);
            v[p][1] = ldb(Uv + (size_t)(bo + i1) * 64 + lane);
            v[p][2] = ldb(Uv + (size_t)(bo + i2) * 64 + lane);
            v[p][3] = ldb(Uv + (size_t)(bo + i3) * 64 + lane);
            v[p][4] = ldb(Uv + (size_t)(bo + i4) * 64 + lane);
            v[p][5] = ldb(Uv + (size_t)(bo + i5) * 64 + lane);
        }
        // ---- phase 2: combine + store + stats ----
#pragma unroll
        for (int p = 0; p < 8; ++p) {
            const int g = gb + p;
            float h = u[p] + ((v[p][0] + v[p][1]) + (v[p][2] + v[p][3]))
                           + (v[p][4] + v[p][5]);
            if (g < TOT) {
                hT[(size_t)g * 64 + lane] = (ushort)f2bu(h);
                float rv = fmaxf(h, 0.f);
                sA += rv;
                sB  = fmaf(rv, rv, sB);
            }
        }
    }

    red[wave][lane]      = sA;
    red[wave][64 + lane] = sB;
    __syncthreads();
    if (threadIdx.x < 128) {
        float vsum = red[0][threadIdx.x] + red[1][threadIdx.x]
                   + red[2][threadIdx.x] + red[3][threadIdx.x];
        partials[(size_t)blockIdx.x * 128 + threadIdx.x] = vsum;
    }
}

// ---------------------------------------------------------------------------
// bnprep: reduce partials -> BN (a,b); emit Wf1 = swizzled a_c*W1 and
// bias[128] = [ sum_c b_c*We1[c][o] | sum_c b_c*Wo1[c][o] ].
// ---------------------------------------------------------------------------
#define G1BLOCKS 1563
__global__ __launch_bounds__(256) void bnprep_k(
    const float* __restrict__ partials, const float* __restrict__ gamma,
    const float* __restrict__ beta, const float* __restrict__ W1,
    ushort* __restrict__ Wf1, float* __restrict__ bias)
{
    __shared__ float ps[2][128];
    __shared__ float a_s[64], b_s[64];
    const int tid = threadIdx.x;

    // two-stage sum over 1563 block-partials (coalesced: stride 128 floats)
    {
        const int ch = tid & 127, half = tid >> 7;
        float s = 0.f;
        for (int i = half; i < G1BLOCKS; i += 2)
            s += partials[(size_t)i * 128 + ch];
        ps[half][ch] = s;
    }
    __syncthreads();
    if (tid < 64) {
        const float inv = 1.f / (float)TOT;
        float mean = (ps[0][tid] + ps[1][tid]) * inv;
        float msq  = (ps[0][64 + tid] + ps[1][64 + tid]) * inv;
        float var  = msq - mean * mean;                 // biased var (jnp.var)
        float a    = gamma[tid] * rsqrtf(var + EPSV);
        a_s[tid] = a;
        b_s[tid] = fmaf(-a, mean, beta[tid]);
    }
    __syncthreads();

    for (int L = tid; L < 8192; L += 256) {
        int i = L & 7, lane = (L >> 3) & 63, r = L >> 9;
        int s = r & 1, t = r >> 1;
        int o = (t & 3) * 16 + (lane & 15);
        int c = s * 32 + (lane >> 4) * 8 + i;
        Wf1[L] = f2bu(a_s[c] * W1[o * 128 + c * 2 + (t >> 2)]);
    }
    if (tid < 128) {
        const int part = tid >> 6, o = tid & 63;
        float s = 0.f;
        for (int c = 0; c < 64; ++c)
            s = fmaf(b_s[c], W1[o * 128 + c * 2 + part], s);
        bias[tid] = s;
    }
}

// ---------------------------------------------------------------------------
// GEMM2: Up[g] = relu(hT[g])·We1' + biasE ; Uq[g] = relu(hT[g])·Wo1' + biasO.
// ---------------------------------------------------------------------------
__global__ __launch_bounds__(256, 3) void gemm2_k(
    const ushort* __restrict__ hT, const ushort* __restrict__ Wf,
    const float* __restrict__ bias, ushort* __restrict__ Up,
    ushort* __restrict__ Uq)
{
    const int wave = threadIdx.x >> 6;
    const int lane = threadIdx.x & 63;
    const int col  = lane & 15;
    const int quad = lane >> 4;

    short8 wf[8][2];
#pragma unroll
    for (int t = 0; t < 8; ++t)
#pragma unroll
        for (int s = 0; s < 2; ++s)
            wf[t][s] = *(const short8*)(Wf + ((t * 2 + s) * 64 + lane) * 8);

    float4v binit[8];
#pragma unroll
    for (int t = 0; t < 8; ++t)
#pragma unroll
        for (int r = 0; r < 4; ++r)
            binit[t][r] = bias[t * 16 + quad * 4 + r];

    const int wid = blockIdx.x * 4 + wave;
    for (int tile = wid; tile < 25000; tile += 2500) {
        const size_t g0 = (size_t)tile * 16;
        const ushort* ar = hT + (g0 + col) * 64 + quad * 8;
        U4S8 p0, p1;
        p0.u = *(const uint4*)(ar);
        p1.u = *(const uint4*)(ar + 32);
        p0.u.x = relu2(p0.u.x); p0.u.y = relu2(p0.u.y);
        p0.u.z = relu2(p0.u.z); p0.u.w = relu2(p0.u.w);
        p1.u.x = relu2(p1.u.x); p1.u.y = relu2(p1.u.y);
        p1.u.z = relu2(p1.u.z); p1.u.w = relu2(p1.u.w);

        float4v acc[8];
#pragma unroll
        for (int t = 0; t < 8; ++t) acc[t] = binit[t];
#pragma unroll
        for (int t = 0; t < 8; ++t)
            acc[t] = __builtin_amdgcn_mfma_f32_16x16x32_bf16(wf[t][0], p0.s, acc[t], 0, 0, 0);
#pragma unroll
        for (int t = 0; t < 8; ++t)
            acc[t] = __builtin_amdgcn_mfma_f32_16x16x32_bf16(wf[t][1], p1.s, acc[t], 0, 0, 0);

#pragma unroll
        for (int t = 0; t < 8; ++t) {
            uint2 d;
            d.x = pk(acc[t][0], acc[t][1]);
            d.y = pk(acc[t][2], acc[t][3]);
            ushort* base = (t < 4) ? Up : Uq;
            *(uint2*)(base + (g0 + col) * 64 + (t & 3) * 16 + quad * 4) = d;
        }
    }
}

// ---------------------------------------------------------------------------
// gather2: out[b][c][n] = relu( p[g] + sum_k q[nb_k] + hT[g] ). Same batched
// wave-uniform gather as gather1; result staged in a 64x64 LDS tile and
// stored transposed (256-B coalesced rows of [B,O,N] f32).
// ---------------------------------------------------------------------------
__global__ __launch_bounds__(256, 4) void gather2_k(
    const ushort* __restrict__ Up, const ushort* __restrict__ Uq,
    const ushort* __restrict__ hT, const int* __restrict__ neigh,
    float* __restrict__ out)
{
    __shared__ float ts[64][65];
    const int wave = threadIdx.x >> 6;
    const int lane = threadIdx.x & 63;
    const int g0   = blockIdx.x * 64;                 // 6250 blocks, exact

    for (int it = 0; it < 2; ++it) {
        float u[8], res[8], q[8][6];
#pragma unroll
        for (int p = 0; p < 8; ++p) {
            const int pl = wave * 16 + it * 8 + p;
            const int g  = g0 + pl;
            const int bo = batch_base(g);
            const int* nb = neigh + (size_t)g * 6;
            u[p]   = ldb(Up + (size_t)g * 64 + lane);
            res[p] = ldb(hT + (size_t)g * 64 + lane);
            int i0 = nb[0], i1 = nb[1], i2 = nb[2], i3 = nb[3], i4 = nb[4], i5 = nb[5];
            q[p][0] = ldb(Uq + (size_t)(bo + i0) * 64 + lane);
            q[p][1] = ldb(Uq + (size_t)(bo + i1) * 64 + lane);
            q[p][2] = ldb(Uq + (size_t)(bo + i2) * 64 + lane);
            q[p][3] = ldb(Uq + (size_t)(bo + i3) * 64 + lane);
            q[p][4] = ldb(Uq + (size_t)(bo + i4) * 64 + lane);
            q[p][5] = ldb(Uq + (size_t)(bo + i5) * 64 + lane);
        }
#pragma unroll
        for (int p = 0; p < 8; ++p) {
            const int pl = wave * 16 + it * 8 + p;
            float h = u[p] + res[p] + ((q[p][0] + q[p][1]) + (q[p][2] + q[p][3]))
                                    + (q[p][4] + q[p][5]);
            ts[lane][pl] = fmaxf(h, 0.f);             // bank = lane+pl: free
        }
    }
    __syncthreads();

    // store transposed: o = wave*16+r rows, n = lane (per-lane batch split)
    const int g2 = g0 + lane;
    const int bo2 = batch_base(g2);
    const int b2  = (g2 >= 3 * NN) ? 3 : (g2 >= 2 * NN) ? 2 : (g2 >= NN) ? 1 : 0;
    const int n2  = g2 - bo2;
#pragma unroll
    for (int r = 0; r < 16; ++r) {
        const int o = wave * 16 + r;
        out[((size_t)b2 * 64 + o) * NN + n2] = ts[o][lane];
    }
}

// ---------------------------------------------------------------------------
// Workspace (bytes), total ~154.4 MB:
//   [0, 51.2M)        xT (xpose->gemm1), then hT (gather1->gemm2,gather2)
//   [51.2M, 102.4M)   Uu (gemm1->gather1), then Up (gemm2->gather2)
//   [102.4M, 153.6M)  Uv (gemm1->gather1), then Uq (gemm2->gather2)
//   153,600,000 partials[1563*128] f32 (800,256 B)
//   154,400,512 Wf0 bf16[8192]; 154,416,896 Wf1 bf16[8192];
//   154,433,280 bias[128] f32   (end 154,433,792)
// ---------------------------------------------------------------------------
extern "C" void kernel_launch(void* const* d_in, const int* in_sizes, int n_in,
                              void* d_out, int out_size, void* d_ws, size_t ws_size,
                              hipStream_t stream)
{
    const float* x     = (const float*)d_in[0];
    const int*   neigh = (const int*)d_in[1];
    const float* W0    = (const float*)d_in[2];
    const float* W1    = (const float*)d_in[3];
    const float* gamma = (const float*)d_in[4];
    const float* beta  = (const float*)d_in[5];
    float* out = (float*)d_out;

    char* ws = (char*)d_ws;
    ushort* xT       = (ushort*)(ws + 0);
    ushort* hT       = (ushort*)(ws + 0);
    ushort* Uu       = (ushort*)(ws + 51200000);
    ushort* Uv       = (ushort*)(ws + 102400000);
    ushort* Up       = Uu;
    ushort* Uq       = Uv;
    float*  partials = (float*)(ws + 153600000);
    ushort* Wf0      = (ushort*)(ws + 154400512);
    ushort* Wf1      = (ushort*)(ws + 154416896);
    float*  bias     = (float*)(ws + 154433280);

    wprep0_k<<<dim3(32), dim3(256), 0, stream>>>(W0, Wf0);
    xpose_k<<<dim3((NN + 63) / 64, BB), dim3(256), 0, stream>>>(x, xT);
    gemm1_k<<<dim3(625), dim3(256), 0, stream>>>(xT, Wf0, Uu, Uv);
    gather1_k<<<dim3(G1BLOCKS), dim3(256), 0, stream>>>(Uu, Uv, neigh, hT, partials);
    bnprep_k<<<dim3(1), dim3(256), 0, stream>>>(partials, gamma, beta, W1, Wf1, bias);
    gemm2_k<<<dim3(625), dim3(256), 0, stream>>>(hT, Wf1, bias, Up, Uq);
    gather2_k<<<dim3(TOT / 64), dim3(256), 0, stream>>>(Up, Uq, hT, neigh, out);
}

// Round 5
// 432.817 us; speedup vs baseline: 3.1099x; 1.6605x over previous
//
#include <hip/hip_runtime.h>
#include <hip/hip_bf16.h>

// Problem constants: B=4, C_IN=C_OUT=64, N=100000, K=6
#define BB   4
#define NN   100000
#define TOT  (BB * NN)          // 400000
#define KK   6
#define EPSV 1e-5f

using bf16   = __hip_bfloat16;
using ushort = unsigned short;
typedef __attribute__((ext_vector_type(8))) short  short8;   // 8 bf16 = 4 VGPRs
typedef __attribute__((ext_vector_type(4))) float  float4v;  // MFMA C/D

union U4S8 { uint4 u; short8 s; };

__device__ __forceinline__ unsigned f2bu(float f) {          // f32 -> raw bf16 RNE
    union { bf16 h; ushort u; } c; c.h = __float2bfloat16(f); return c.u;
}
__device__ __forceinline__ unsigned pk(float a, float b) {
    return f2bu(a) | (f2bu(b) << 16);
}
__device__ __forceinline__ float blo(unsigned x) {           // low bf16 -> f32
    union { unsigned u; float f; } c; c.u = x << 16; return c.f;
}
__device__ __forceinline__ float bhi(unsigned x) {           // high bf16 -> f32
    union { unsigned u; float f; } c; c.u = x & 0xFFFF0000u; return c.f;
}
__device__ __forceinline__ unsigned relu2(unsigned x) {      // relu on packed 2xbf16
    unsigned lo = (unsigned)(((int)(x << 16)) >> 31) & 0x0000FFFFu;
    unsigned hi = ((unsigned)(((int)x) >> 31)) << 16;
    return x & ~(lo | hi);
}
__device__ __forceinline__ int batch_base(int g) {           // (g/NN)*NN via compares
    return (g >= 3 * NN) ? 3 * NN : (g >= 2 * NN) ? 2 * NN : (g >= NN) ? NN : 0;
}

// ---------------------------------------------------------------------------
// wprep0: swizzle W0[o][c][2] into MFMA M-operand (B-role) fragments.
// Wf0[((t*2+s)*64+lane)*8+i] = W0[o=(t&3)*16+(lane&15)][c=s*32+(lane>>4)*8+i][t>>2]
// tiles t<4 -> u = x·We (center), t>=4 -> v = x·Wo (neighbor operator).
// ---------------------------------------------------------------------------
__global__ void wprep0_k(const float* __restrict__ W0, ushort* __restrict__ Wf0)
{
    int L = blockIdx.x * 256 + threadIdx.x;        // 8192
    if (L < 8192) {
        int i = L & 7, lane = (L >> 3) & 63, r = L >> 9;
        int s = r & 1, t = r >> 1;
        int o = (t & 3) * 16 + (lane & 15);
        int c = s * 32 + (lane >> 4) * 8 + i;
        Wf0[L] = f2bu(W0[o * 128 + c * 2 + (t >> 2)]);
    }
}

// ---------------------------------------------------------------------------
// xpose: x [B,C,N] f32 -> xT [B,N,C] bf16.
// ---------------------------------------------------------------------------
__global__ __launch_bounds__(256) void xpose_k(const float* __restrict__ x,
                                               ushort* __restrict__ xT)
{
    __shared__ float tile[64][65];
    const int b  = blockIdx.y;
    const int n0 = blockIdx.x * 64;
    const int tx = threadIdx.x & 63;
    const int ty = threadIdx.x >> 6;
    const float* xb = x + (size_t)b * 64 * NN;
    const int n = n0 + tx;
#pragma unroll
    for (int cc = 0; cc < 64; cc += 4) {
        const int c = cc + ty;
        tile[tx][c] = (n < NN) ? xb[(size_t)c * NN + n] : 0.f;
    }
    __syncthreads();
#pragma unroll
    for (int rr = 0; rr < 64; rr += 4) {
        const int nl = rr + ty;
        const int n2 = n0 + nl;
        if (n2 < NN) xT[((size_t)b * NN + n2) * 64 + tx] = (ushort)f2bu(tile[nl][tx]);
    }
}

// ---------------------------------------------------------------------------
// GEMM1: Uu[g][64] = xT[g]·We ; Uv[g][64] = xT[g]·Wo  (bf16 rows, 128 B).
// Streaming MFMA: weights in 64 VGPRs, A-frags direct global b128, no LDS.
// ---------------------------------------------------------------------------
__global__ __launch_bounds__(256, 3) void gemm1_k(
    const ushort* __restrict__ xT, const ushort* __restrict__ Wf,
    ushort* __restrict__ Uu, ushort* __restrict__ Uv)
{
    const int wave = threadIdx.x >> 6;
    const int lane = threadIdx.x & 63;
    const int col  = lane & 15;
    const int quad = lane >> 4;

    short8 wf[8][2];
#pragma unroll
    for (int t = 0; t < 8; ++t)
#pragma unroll
        for (int s = 0; s < 2; ++s)
            wf[t][s] = *(const short8*)(Wf + ((t * 2 + s) * 64 + lane) * 8);

    const int wid = blockIdx.x * 4 + wave;            // 2500 waves, 10 tiles each
    for (int tile = wid; tile < 25000; tile += 2500) {
        const size_t g0 = (size_t)tile * 16;
        const ushort* ar = xT + (g0 + col) * 64 + quad * 8;
        short8 p0 = *(const short8*)(ar);
        short8 p1 = *(const short8*)(ar + 32);

        float4v acc[8];
#pragma unroll
        for (int t = 0; t < 8; ++t) acc[t] = (float4v){0.f, 0.f, 0.f, 0.f};
#pragma unroll
        for (int t = 0; t < 8; ++t)
            acc[t] = __builtin_amdgcn_mfma_f32_16x16x32_bf16(wf[t][0], p0, acc[t], 0, 0, 0);
#pragma unroll
        for (int t = 0; t < 8; ++t)
            acc[t] = __builtin_amdgcn_mfma_f32_16x16x32_bf16(wf[t][1], p1, acc[t], 0, 0, 0);

        // D[row=quad*4+r -> ch][col -> point]
#pragma unroll
        for (int t = 0; t < 8; ++t) {
            uint2 d;
            d.x = pk(acc[t][0], acc[t][1]);
            d.y = pk(acc[t][2], acc[t][3]);
            ushort* base = (t < 4) ? Uu : Uv;
            *(uint2*)(base + (g0 + col) * 64 + (t & 3) * 16 + quad * 4) = d;
        }
    }
}

// ---------------------------------------------------------------------------
// gather1: h[g] = u[g] + sum_k v[nb_k].  4 points per load instruction:
// 16 lanes x 8 B = one 128-B row; quarter q = point, cpos = 4-channel chunk.
// Per 8-point group: 12 idx loads + 14 dwordx2 data loads, fully batched.
// Block-local stats reduction -> 128 atomicAdds (device scope).
// ---------------------------------------------------------------------------
__global__ __launch_bounds__(256, 4) void gather1_k(
    const ushort* __restrict__ Uu, const ushort* __restrict__ Uv,
    const int* __restrict__ neigh, ushort* __restrict__ hT,
    float* __restrict__ stats)
{
    __shared__ float red[4][128];
    const int wave = threadIdx.x >> 6;
    const int lane = threadIdx.x & 63;
    const int q    = lane >> 4;          // point-within-instruction
    const int cpos = lane & 15;          // channel chunk: ch = cpos*4 .. +3
    const int g0   = (blockIdx.x * 4 + wave) * 64;

    float sA[4] = {0, 0, 0, 0}, sB[4] = {0, 0, 0, 0};

    for (int it = 0; it < 8; ++it) {
        const int gb = g0 + it * 8;
        int gp[2], gc[2], bo[2];
        gp[0] = gb + q;     gp[1] = gb + 4 + q;
        gc[0] = (gp[0] < TOT) ? gp[0] : (TOT - 1);
        gc[1] = (gp[1] < TOT) ? gp[1] : (TOT - 1);
        bo[0] = batch_base(gc[0]);
        bo[1] = batch_base(gc[1]);

        // phase 0: neighbor indices (16-way broadcast per instruction)
        int idx[2][6];
#pragma unroll
        for (int i = 0; i < 2; ++i)
#pragma unroll
            for (int k = 0; k < 6; ++k)
                idx[i][k] = neigh[(size_t)gc[i] * 6 + k];

        // phase 1: batch-issue all data loads (2 u + 12 v, 512 B each)
        uint2 uu[2], vv[2][6];
#pragma unroll
        for (int i = 0; i < 2; ++i)
            uu[i] = *(const uint2*)(Uu + (size_t)gc[i] * 64 + cpos * 4);
#pragma unroll
        for (int i = 0; i < 2; ++i)
#pragma unroll
            for (int k = 0; k < 6; ++k)
                vv[i][k] = *(const uint2*)(Uv + (size_t)(bo[i] + idx[i][k]) * 64 + cpos * 4);

        // phase 2: combine + store + stats
#pragma unroll
        for (int i = 0; i < 2; ++i) {
            float h[4];
            h[0] = blo(uu[i].x); h[1] = bhi(uu[i].x);
            h[2] = blo(uu[i].y); h[3] = bhi(uu[i].y);
#pragma unroll
            for (int k = 0; k < 6; ++k) {
                h[0] += blo(vv[i][k].x); h[1] += bhi(vv[i][k].x);
                h[2] += blo(vv[i][k].y); h[3] += bhi(vv[i][k].y);
            }
            if (gp[i] < TOT) {
                uint2 st;
                st.x = pk(h[0], h[1]);
                st.y = pk(h[2], h[3]);
                *(uint2*)(hT + (size_t)gp[i] * 64 + cpos * 4) = st;
#pragma unroll
                for (int j = 0; j < 4; ++j) {
                    float rv = fmaxf(h[j], 0.f);
                    sA[j] += rv;
                    sB[j]  = fmaf(rv, rv, sB[j]);
                }
            }
        }
    }

    // reduce across the 4 quarters (lane bits 4,5) — outside all load chains
#pragma unroll
    for (int d = 16; d < 64; d <<= 1)
#pragma unroll
        for (int j = 0; j < 4; ++j) {
            sA[j] += __shfl_xor(sA[j], d);
            sB[j] += __shfl_xor(sB[j], d);
        }
    if (q == 0) {
#pragma unroll
        for (int j = 0; j < 4; ++j) {
            red[wave][cpos * 4 + j]      = sA[j];
            red[wave][64 + cpos * 4 + j] = sB[j];
        }
    }
    __syncthreads();
    if (threadIdx.x < 128) {
        float v = red[0][threadIdx.x] + red[1][threadIdx.x]
                + red[2][threadIdx.x] + red[3][threadIdx.x];
        atomicAdd(&stats[threadIdx.x], v);   // 128 addrs/block, device scope
    }
}

// ---------------------------------------------------------------------------
// bnA: stats -> per-channel affine  rhat = a*relu(h) + b.   (1 block, ~2 us)
// ---------------------------------------------------------------------------
__global__ void bnA_k(const float* __restrict__ stats, const float* __restrict__ gamma,
                      const float* __restrict__ beta, float* __restrict__ ab)
{
    const int o = threadIdx.x;
    if (o < 64) {
        const float inv = 1.f / (float)TOT;
        float mean = stats[o] * inv;
        float var  = stats[64 + o] * inv - mean * mean;   // biased var (jnp.var)
        float a    = gamma[o] * rsqrtf(var + EPSV);
        ab[o]      = a;
        ab[64 + o] = fmaf(-a, mean, beta[o]);
    }
}

// ---------------------------------------------------------------------------
// bnB: parallel Wf1 swizzle (blocks 0..31) + bias dots (block 32).
// Wf1 = swizzled a_c*W1; bias[128] = [ sum_c b_c*We1[c][o] | sum_c b_c*Wo1 ].
// ---------------------------------------------------------------------------
__global__ __launch_bounds__(256) void bnB_k(
    const float* __restrict__ ab, const float* __restrict__ W1,
    ushort* __restrict__ Wf1, float* __restrict__ bias)
{
    if (blockIdx.x < 32) {
        int L = blockIdx.x * 256 + threadIdx.x;   // 8192
        int i = L & 7, lane = (L >> 3) & 63, r = L >> 9;
        int s = r & 1, t = r >> 1;
        int o = (t & 3) * 16 + (lane & 15);
        int c = s * 32 + (lane >> 4) * 8 + i;
        Wf1[L] = f2bu(ab[c] * W1[o * 128 + c * 2 + (t >> 2)]);
    } else if (threadIdx.x < 128) {
        const int part = threadIdx.x >> 6, o = threadIdx.x & 63;
        float s = 0.f;
#pragma unroll
        for (int c = 0; c < 64; ++c)
            s = fmaf(ab[64 + c], W1[o * 128 + c * 2 + part], s);
        bias[threadIdx.x] = s;
    }
}

// ---------------------------------------------------------------------------
// GEMM2: Up[g] = relu(hT[g])·We1' + biasE ; Uq[g] = relu(hT[g])·Wo1' + biasO.
// ---------------------------------------------------------------------------
__global__ __launch_bounds__(256, 3) void gemm2_k(
    const ushort* __restrict__ hT, const ushort* __restrict__ Wf,
    const float* __restrict__ bias, ushort* __restrict__ Up,
    ushort* __restrict__ Uq)
{
    const int wave = threadIdx.x >> 6;
    const int lane = threadIdx.x & 63;
    const int col  = lane & 15;
    const int quad = lane >> 4;

    short8 wf[8][2];
#pragma unroll
    for (int t = 0; t < 8; ++t)
#pragma unroll
        for (int s = 0; s < 2; ++s)
            wf[t][s] = *(const short8*)(Wf + ((t * 2 + s) * 64 + lane) * 8);

    float4v binit[8];
#pragma unroll
    for (int t = 0; t < 8; ++t)
#pragma unroll
        for (int r = 0; r < 4; ++r)
            binit[t][r] = bias[t * 16 + quad * 4 + r];

    const int wid = blockIdx.x * 4 + wave;
    for (int tile = wid; tile < 25000; tile += 2500) {
        const size_t g0 = (size_t)tile * 16;
        const ushort* ar = hT + (g0 + col) * 64 + quad * 8;
        U4S8 p0, p1;
        p0.u = *(const uint4*)(ar);
        p1.u = *(const uint4*)(ar + 32);
        p0.u.x = relu2(p0.u.x); p0.u.y = relu2(p0.u.y);
        p0.u.z = relu2(p0.u.z); p0.u.w = relu2(p0.u.w);
        p1.u.x = relu2(p1.u.x); p1.u.y = relu2(p1.u.y);
        p1.u.z = relu2(p1.u.z); p1.u.w = relu2(p1.u.w);

        float4v acc[8];
#pragma unroll
        for (int t = 0; t < 8; ++t) acc[t] = binit[t];
#pragma unroll
        for (int t = 0; t < 8; ++t)
            acc[t] = __builtin_amdgcn_mfma_f32_16x16x32_bf16(wf[t][0], p0.s, acc[t], 0, 0, 0);
#pragma unroll
        for (int t = 0; t < 8; ++t)
            acc[t] = __builtin_amdgcn_mfma_f32_16x16x32_bf16(wf[t][1], p1.s, acc[t], 0, 0, 0);

#pragma unroll
        for (int t = 0; t < 8; ++t) {
            uint2 d;
            d.x = pk(acc[t][0], acc[t][1]);
            d.y = pk(acc[t][2], acc[t][3]);
            ushort* base = (t < 4) ? Up : Uq;
            *(uint2*)(base + (g0 + col) * 64 + (t & 3) * 16 + quad * 4) = d;
        }
    }
}

// ---------------------------------------------------------------------------
// gather2: out[b][c][n] = relu( p[g] + sum_k q[nb_k] + hT[g] ).  Same
// 4-points-per-instruction batched gather; LDS-transposed coalesced store.
// ---------------------------------------------------------------------------
__global__ __launch_bounds__(256, 4) void gather2_k(
    const ushort* __restrict__ Up, const ushort* __restrict__ Uq,
    const ushort* __restrict__ hT, const int* __restrict__ neigh,
    float* __restrict__ out)
{
    __shared__ float ts[64][65];
    const int wave = threadIdx.x >> 6;
    const int lane = threadIdx.x & 63;
    const int q    = lane >> 4;
    const int cpos = lane & 15;
    const int g0   = blockIdx.x * 64;                 // 6250 blocks, exact

#pragma unroll
    for (int it = 0; it < 2; ++it) {
        const int gb = g0 + wave * 16 + it * 8;       // 8-pt group, single batch
        int gp[2], bo[2];
        gp[0] = gb + q;  gp[1] = gb + 4 + q;
        bo[0] = batch_base(gp[0]);
        bo[1] = batch_base(gp[1]);

        int idx[2][6];
#pragma unroll
        for (int i = 0; i < 2; ++i)
#pragma unroll
            for (int k = 0; k < 6; ++k)
                idx[i][k] = neigh[(size_t)gp[i] * 6 + k];

        uint2 pp[2], rr[2], qq[2][6];
#pragma unroll
        for (int i = 0; i < 2; ++i) {
            pp[i] = *(const uint2*)(Up + (size_t)gp[i] * 64 + cpos * 4);
            rr[i] = *(const uint2*)(hT + (size_t)gp[i] * 64 + cpos * 4);
        }
#pragma unroll
        for (int i = 0; i < 2; ++i)
#pragma unroll
            for (int k = 0; k < 6; ++k)
                qq[i][k] = *(const uint2*)(Uq + (size_t)(bo[i] + idx[i][k]) * 64 + cpos * 4);

#pragma unroll
        for (int i = 0; i < 2; ++i) {
            float h[4];
            h[0] = blo(pp[i].x) + blo(rr[i].x); h[1] = bhi(pp[i].x) + bhi(rr[i].x);
            h[2] = blo(pp[i].y) + blo(rr[i].y); h[3] = bhi(pp[i].y) + bhi(rr[i].y);
#pragma unroll
            for (int k = 0; k < 6; ++k) {
                h[0] += blo(qq[i][k].x); h[1] += bhi(qq[i][k].x);
                h[2] += blo(qq[i][k].y); h[3] += bhi(qq[i][k].y);
            }
            const int pl = wave * 16 + it * 8 + i * 4 + q;
#pragma unroll
            for (int j = 0; j < 4; ++j)
                ts[cpos * 4 + j][pl] = fmaxf(h[j], 0.f);
        }
    }
    __syncthreads();

    // store transposed: o = wave*16+r rows, n = lane (per-lane batch split)
    const int g2  = g0 + lane;
    const int bo2 = batch_base(g2);
    const int b2  = (g2 >= 3 * NN) ? 3 : (g2 >= 2 * NN) ? 2 : (g2 >= NN) ? 1 : 0;
    const int n2  = g2 - bo2;
#pragma unroll
    for (int r = 0; r < 16; ++r) {
        const int o = wave * 16 + r;
        out[((size_t)b2 * 64 + o) * NN + n2] = ts[o][lane];
    }
}

// ---------------------------------------------------------------------------
// Workspace (bytes), total ~153.7 MB:
//   [0, 51.2M)        xT (xpose->gemm1), then hT (gather1->gemm2,gather2)
//   [51.2M, 102.4M)   Uu (gemm1->gather1), then Up (gemm2->gather2)
//   [102.4M, 153.6M)  Uv (gemm1->gather1), then Uq (gemm2->gather2)
//   153,600,000 stats[128] f32;  153,600,512 ab[128] f32;
//   153,601,024 Wf0 bf16[8192];  153,617,408 Wf1 bf16[8192];
//   153,633,792 bias[128] f32    (end 153,634,304)
// ---------------------------------------------------------------------------
extern "C" void kernel_launch(void* const* d_in, const int* in_sizes, int n_in,
                              void* d_out, int out_size, void* d_ws, size_t ws_size,
                              hipStream_t stream)
{
    const float* x     = (const float*)d_in[0];
    const int*   neigh = (const int*)d_in[1];
    const float* W0    = (const float*)d_in[2];
    const float* W1    = (const float*)d_in[3];
    const float* gamma = (const float*)d_in[4];
    const float* beta  = (const float*)d_in[5];
    float* out = (float*)d_out;

    char* ws = (char*)d_ws;
    ushort* xT    = (ushort*)(ws + 0);
    ushort* hT    = (ushort*)(ws + 0);
    ushort* Uu    = (ushort*)(ws + 51200000);
    ushort* Uv    = (ushort*)(ws + 102400000);
    ushort* Up    = Uu;
    ushort* Uq    = Uv;
    float*  stats = (float*)(ws + 153600000);
    float*  ab    = (float*)(ws + 153600512);
    ushort* Wf0   = (ushort*)(ws + 153601024);
    ushort* Wf1   = (ushort*)(ws + 153617408);
    float*  bias  = (float*)(ws + 153633792);

    hipMemsetAsync(stats, 0, 512, stream);
    wprep0_k<<<dim3(32), dim3(256), 0, stream>>>(W0, Wf0);
    xpose_k<<<dim3((NN + 63) / 64, BB), dim3(256), 0, stream>>>(x, xT);
    gemm1_k<<<dim3(625), dim3(256), 0, stream>>>(xT, Wf0, Uu, Uv);
    gather1_k<<<dim3(1563), dim3(256), 0, stream>>>(Uu, Uv, neigh, hT, stats);
    bnA_k<<<dim3(1), dim3(64), 0, stream>>>(stats, gamma, beta, ab);
    bnB_k<<<dim3(33), dim3(256), 0, stream>>>(ab, W1, Wf1, bias);
    gemm2_k<<<dim3(625), dim3(256), 0, stream>>>(hT, Wf1, bias, Up, Uq);
    gather2_k<<<dim3(TOT / 64), dim3(256), 0, stream>>>(Up, Uq, hT, neigh, out);
}